// Round 20
// baseline (391.847 us; speedup 1.0000x reference)
//
#include <hip/hip_runtime.h>

#define CLK_NATOMS 8192
#define CLK_NSHIFT 14
#define CLK_NROWS (CLK_NSHIFT * CLK_NATOMS)  // 114688 rows = (k, i)
#define CLK_NTILE 112                        // tiles of 1024 rows
#define CLK_NCELL 512                        // 8x8x8 spatial bins
#define CLK_CAP 128                          // max hits per row (k=0 max ~90)
#define CLK_PWAVES 8192                      // persistent waves (1024 blk x 8)
#define CLK_C2 ((float)(5.2 * 5.2))          // f32 compare (JAX weak promotion)
#define CLK_R 5.35f                          // candidate interval half-width

__device__ const int clk_shifts[CLK_NSHIFT][3] = {
    {0, 0, 0},
    {-1, 0, 0}, {-1, -1, 0}, {0, -1, 0}, {1, -1, 0},
    {-1, 1, -1}, {0, 1, -1}, {1, 1, -1}, {-1, 0, -1},
    {0, 0, -1}, {1, 0, -1}, {-1, -1, -1}, {0, -1, -1}, {1, -1, -1}};

// Module-owned scratch (d_ws unused). Everything read is rewritten each call.
__device__ float4 clk_pp[CLK_NATOMS];      // wrapped coords
__device__ int clk_cid[CLK_NATOMS];        // cell id per atom
__device__ float4 clk_sorted[CLK_NATOMS];  // bin-sorted coords, .w = original i
__device__ unsigned clk_cstart[CLK_NCELL + 1];
__device__ unsigned clk_cfill[CLK_NCELL];
__device__ unsigned clk_nalive;            // alive-row count
__device__ unsigned clk_alist[CLK_NROWS];  // alive row ids (k<<13 | i)
__device__ int clk_jbuf[(size_t)CLK_NROWS * CLK_CAP];  // per-row sorted hit j's
__device__ unsigned clk_cnt[CLK_NROWS];
__device__ unsigned clk_pend[CLK_NTILE];   // alive rows remaining per tile
__device__ unsigned clk_tstat[CLK_NTILE];  // per-tile totals (count publishes)
__device__ float4 clk_dg;                  // cell diagonal
__device__ float4 clk_cinv;                // 8/diag per axis
__device__ float4 clk_sf[CLK_NSHIFT];      // s * diag (f32, __fmul_rn)

// Slab prune: d2<=c2 forces shifted atom i into a cutoff-wide boundary slab.
__device__ __forceinline__ bool clk_alive_f(float xi, float yi, float zi, int sx,
                                            int sy, int sz, float dgx, float dgy,
                                            float dgz) {
  bool a = true;
  if (sx < 0) a = a && (xi >= dgx - 5.3f); else if (sx > 0) a = a && (xi <= 5.3f);
  if (sy < 0) a = a && (yi >= dgy - 5.3f); else if (sy > 0) a = a && (yi <= 5.3f);
  if (sz < 0) a = a && (zi >= dgz - 5.3f); else if (sz > 0) a = a && (zi <= 5.3f);
  return a;
}

// Candidate cell range on one axis (monotone-rounding safe, 0.14 slack).
__device__ __forceinline__ void clk_crange(float t, float ci, int& lo, int& hi) {
  lo = max(0, (int)(fmaxf(t - CLK_R, 0.f) * ci));
  hi = min(7, (int)(fmaxf(t + CLK_R, 0.f) * ci));
}

__device__ __forceinline__ unsigned clk_iscan(unsigned v, int lane) {
  for (int off = 1; off < 64; off <<= 1) {
    unsigned t = __shfl_up(v, off);
    if (lane >= off) v += t;
  }
  return v;
}

// --- L1: wrap + cell-id; zero cnt/pend/tstat/nalive; publish constants ------
// frac = x @ inv(cell); frac -= floor(frac); w = frac @ cell   (f32 per-op RN)
__global__ __launch_bounds__(256) void clk_wrapbin(const float* __restrict__ coords,
                                                   const float* __restrict__ cell) {
  int i = blockIdx.x * blockDim.x + threadIdx.x;
  if (i >= CLK_NATOMS) return;
  if (i < CLK_NTILE) {
    clk_pend[i] = 0u;
    clk_tstat[i] = 0u;
  }
  if (i == 0) clk_nalive = 0u;
#pragma unroll
  for (int k = 0; k < CLK_NSHIFT; ++k) clk_cnt[(k << 13) + i] = 0u;  // coalesced

  float dgx = (float)sqrt((double)cell[0] * cell[0] + (double)cell[3] * cell[3] +
                          (double)cell[6] * cell[6]);
  float dgy = (float)sqrt((double)cell[1] * cell[1] + (double)cell[4] * cell[4] +
                          (double)cell[7] * cell[7]);
  float dgz = (float)sqrt((double)cell[2] * cell[2] + (double)cell[5] * cell[5] +
                          (double)cell[8] * cell[8]);
  float cix = 8.0f / dgx, ciy = 8.0f / dgy, ciz = 8.0f / dgz;
  if (i == 0) {
    clk_dg = make_float4(dgx, dgy, dgz, 0.f);
    clk_cinv = make_float4(cix, ciy, ciz, 0.f);
    for (int k = 0; k < CLK_NSHIFT; ++k)
      clk_sf[k] = make_float4(__fmul_rn((float)clk_shifts[k][0], dgx),
                              __fmul_rn((float)clk_shifts[k][1], dgy),
                              __fmul_rn((float)clk_shifts[k][2], dgz), 0.f);
  }

  double a00 = cell[0], a01 = cell[1], a02 = cell[2];
  double a10 = cell[3], a11 = cell[4], a12 = cell[5];
  double a20 = cell[6], a21 = cell[7], a22 = cell[8];
  double det = a00 * (a11 * a22 - a12 * a21) - a01 * (a10 * a22 - a12 * a20) +
               a02 * (a10 * a21 - a11 * a20);
  double id = 1.0 / det;
  float inv[3][3];
  inv[0][0] = (float)((a11 * a22 - a12 * a21) * id);
  inv[0][1] = (float)(-(a01 * a22 - a02 * a21) * id);
  inv[0][2] = (float)((a01 * a12 - a02 * a11) * id);
  inv[1][0] = (float)(-(a10 * a22 - a12 * a20) * id);
  inv[1][1] = (float)((a00 * a22 - a02 * a20) * id);
  inv[1][2] = (float)(-(a00 * a12 - a02 * a10) * id);
  inv[2][0] = (float)((a10 * a21 - a11 * a20) * id);
  inv[2][1] = (float)(-(a00 * a21 - a01 * a20) * id);
  inv[2][2] = (float)((a00 * a11 - a01 * a10) * id);

  float x = coords[3 * i], y = coords[3 * i + 1], z = coords[3 * i + 2];
  float fr[3], w[3];
#pragma unroll
  for (int c = 0; c < 3; ++c) {
    float f = __fadd_rn(__fadd_rn(__fmul_rn(x, inv[0][c]), __fmul_rn(y, inv[1][c])),
                        __fmul_rn(z, inv[2][c]));
    fr[c] = __fsub_rn(f, floorf(f));
  }
#pragma unroll
  for (int c = 0; c < 3; ++c) {
    w[c] = __fadd_rn(
        __fadd_rn(__fmul_rn(fr[0], cell[0 * 3 + c]), __fmul_rn(fr[1], cell[1 * 3 + c])),
        __fmul_rn(fr[2], cell[2 * 3 + c]));
  }
  clk_pp[i] = make_float4(w[0], w[1], w[2], 0.0f);
  int cx = min(7, (int)(w[0] * cix));
  int cy = min(7, (int)(w[1] * ciy));
  int cz = min(7, (int)(w[2] * ciz));
  clk_cid[i] = (cz * 8 + cy) * 8 + cx;  // x fastest -> contiguous x-runs
}

// --- L2: LDS histogram from cid + exclusive scan of 512 cell counts ---------
__global__ __launch_bounds__(1024) void clk_cscan() {
  __shared__ unsigned h[CLK_NCELL];
  int t = threadIdx.x;
  if (t < CLK_NCELL) h[t] = 0u;
  __syncthreads();
#pragma unroll
  for (int r = 0; r < 8; ++r) atomicAdd(&h[clk_cid[t + r * 1024]], 1u);
  __syncthreads();
  unsigned v = (t < CLK_NCELL) ? h[t] : 0u;
  unsigned acc = v;
  for (int off = 1; off < CLK_NCELL; off <<= 1) {
    unsigned a = (t >= off && t < CLK_NCELL) ? h[t - off] : 0u;
    __syncthreads();
    if (t < CLK_NCELL) {
      acc += a;
      h[t] = acc;
    }
    __syncthreads();
  }
  if (t < CLK_NCELL) {
    clk_cstart[t] = acc - v;
    clk_cfill[t] = acc - v;
  }
  if (t == CLK_NCELL - 1) clk_cstart[CLK_NCELL] = acc;
}

// --- L3: scatter (bin-sort) + alive-row list + per-tile alive counts --------
// (intra-cell order and alist order nondeterministic; both output-invariant)
__global__ __launch_bounds__(256) void clk_scatter() {
  int i = blockIdx.x * blockDim.x + threadIdx.x;
  if (i >= CLK_NATOMS) return;
  float4 p = clk_pp[i];
  unsigned pos = atomicAdd(&clk_cfill[clk_cid[i]], 1u);
  float4 ps = p;
  ps.w = __int_as_float(i);
  clk_sorted[pos] = ps;

  float4 dg = clk_dg;
  unsigned rows[CLK_NSHIFT];
  int m = 0;
  rows[m++] = (unsigned)i;  // k = 0 always alive
#pragma unroll
  for (int k = 1; k < CLK_NSHIFT; ++k) {
    if (clk_alive_f(p.x, p.y, p.z, clk_shifts[k][0], clk_shifts[k][1],
                    clk_shifts[k][2], dg.x, dg.y, dg.z))
      rows[m++] = (unsigned)((k << 13) + i);
  }
  unsigned base = atomicAdd(&clk_nalive, (unsigned)m);
  for (int q = 0; q < m; ++q) {
    clk_alist[base + q] = rows[q];
    atomicAdd(&clk_pend[rows[q] >> 10], 1u);
  }
}

// --- L4: count: persistent waves over ALIVE rows; per row: cell-list
// candidates -> LDS bitmask -> sorted compact j-list + count. After EVERY row
// (processed or empty): fence + pend decrement; the last wave of a tile
// reduces the tile's 1024 counts and publishes tstat (read next kernel,
// NO spinning). Divergence-safe: decrement lane-0 + shuffle broadcast. -------
__global__ __launch_bounds__(512) void clk_count() {
  __shared__ uint4 smask[8][64];  // 1KB mask per wave
  int wslot = threadIdx.x >> 6;
  int lane = threadIdx.x & 63;
  unsigned* lm = (unsigned*)smask[wslot];
  unsigned na = clk_nalive;
  float4 cinv = clk_cinv;

  for (unsigned w = blockIdx.x * 8 + wslot; w < na; w += CLK_PWAVES) {
    unsigned row = clk_alist[w];
    int k = row >> 13, i = row & (CLK_NATOMS - 1);
    float4 sc = clk_sf[k];
    float4 pi = clk_pp[i];
    smask[wslot][lane] = make_uint4(0u, 0u, 0u, 0u);

    int xlo, xhi, ylo, yhi, zlo, zhi;
    clk_crange(__fadd_rn(pi.x, sc.x), cinv.x, xlo, xhi);
    clk_crange(__fadd_rn(pi.y, sc.y), cinv.y, ylo, yhi);
    clk_crange(__fadd_rn(pi.z, sc.z), cinv.z, zlo, zhi);

    for (int cz = zlo; cz <= zhi; ++cz) {
      for (int cy = ylo; cy <= yhi; ++cy) {
        int idb = (cz * 8 + cy) * 8;
        unsigned b = clk_cstart[idb + xlo], e = clk_cstart[idb + xhi + 1];
        for (unsigned t = b + lane; t < e; t += 64) {
          float4 pj = clk_sorted[t];
          int j = __float_as_int(pj.w);
          float dx = __fadd_rn(__fsub_rn(pi.x, pj.x), sc.x);
          float dy = __fadd_rn(__fsub_rn(pi.y, pj.y), sc.y);
          float dz = __fadd_rn(__fsub_rn(pi.z, pj.z), sc.z);
          float d2 = __fadd_rn(__fadd_rn(__fmul_rn(dx, dx), __fmul_rn(dy, dy)),
                               __fmul_rn(dz, dz));
          bool ok = (d2 <= CLK_C2) && (k != 0 || i < j);
          if (ok) atomicOr(&lm[(unsigned)j >> 5], 1u << (j & 31));
        }
      }
    }
    __threadfence_block();  // drain LDS atomics; all lanes reconverged here

    const unsigned long long* mrow = (const unsigned long long*)lm;
    unsigned long long m0 = mrow[lane];       // j in [64*lane, 64*lane+64)
    unsigned long long m1 = mrow[64 + lane];  // j in [4096+64*lane, ...)
    bool have = (__ballot((m0 | m1) != 0ull) != 0ull);  // wave-uniform
    if (have) {
      unsigned c0 = (unsigned)__popcll(m0), c1 = (unsigned)__popcll(m1);
      unsigned s0 = clk_iscan(c0, lane);
      unsigned T0 = __shfl(s0, 63);
      unsigned e0 = s0 - c0;
      unsigned s1 = clk_iscan(c1, lane);
      unsigned T1 = __shfl(s1, 63);
      unsigned e1 = T0 + s1 - c1;

      size_t jb = (size_t)row * CLK_CAP;
      unsigned p = e0;
      unsigned long long m = m0;
      while (m) {
        int b = __ffsll((long long)m) - 1;
        m &= m - 1;
        if (p < CLK_CAP) clk_jbuf[jb + p] = (lane << 6) + b;
        ++p;
      }
      p = e1;
      m = m1;
      while (m) {
        int b = __ffsll((long long)m) - 1;
        m &= m - 1;
        if (p < CLK_CAP) clk_jbuf[jb + p] = ((64 + lane) << 6) + b;
        ++p;
      }
      if (lane == 0) clk_cnt[row] = min(T0 + T1, (unsigned)CLK_CAP);
    }
    // pend decrement ALWAYS (all lanes reconverged; lane-0 atomic + broadcast)
    int tile = (int)(row >> 10);
    unsigned left = 0;
    if (lane == 0) {
      __threadfence();  // release our cnt write
      left = atomicSub(&clk_pend[tile], 1u);
    }
    left = __shfl(left, 0);
    if (left == 1u) {   // we closed this tile: publish its total
      __threadfence();  // acquire all other waves' cnt writes
      unsigned tb = (unsigned)tile << 10;
      unsigned s = 0;
#pragma unroll
      for (int q = 0; q < 16; ++q) s += clk_cnt[tb + lane + (q << 6)];
#pragma unroll
      for (int off = 32; off; off >>= 1) s += __shfl_down(s, off);
      if (lane == 0) clk_tstat[tile] = s;  // read after kernel boundary
    }
  }
}

// --- L5: emit: persistent waves over alive rows; per row: tile base from
// tstat prefix (<=112, L2-hot) + within-tile exclusive offset summed directly
// from cnt (<=16 loads/lane), then lanes copy the compact j-list into
// [ i xP | j xP | (sx,sy,sz) xP ] coalesced ----------------------------------
__global__ __launch_bounds__(512) void clk_emit(int* __restrict__ out, int P) {
  int wslot = threadIdx.x >> 6;
  int lane = threadIdx.x & 63;
  unsigned na = clk_nalive;

  for (unsigned w = blockIdx.x * 8 + wslot; w < na; w += CLK_PWAVES) {
    unsigned row = clk_alist[w];
    unsigned c = clk_cnt[row];  // wave-uniform load
    if (c == 0) continue;       // uniform branch
    int tile = (int)(row >> 10);
    unsigned tb = (unsigned)tile << 10;
    unsigned local = row & 1023u;

    unsigned v = 0;
    if (lane < tile) v = clk_tstat[lane];
    if (64 + lane < tile) v += clk_tstat[64 + lane];
    for (unsigned q = lane; q < local; q += 64) v += clk_cnt[tb + q];
#pragma unroll
    for (int off = 32; off; off >>= 1) v += __shfl_down(v, off);
    unsigned off0 = __shfl(v, 0);

    int k = row >> 13, i = row & (CLK_NATOMS - 1);
    int sx = clk_shifts[k][0], sy = clk_shifts[k][1], sz = clk_shifts[k][2];
    size_t jb = (size_t)row * CLK_CAP;
    for (unsigned q = lane; q < c; q += 64) {
      unsigned p = off0 + q;
      if (p < (unsigned)P) {
        out[p] = i;
        out[P + p] = clk_jbuf[jb + q];
        unsigned sp = 2u * (unsigned)P + 3u * p;
        out[sp] = sx;
        out[sp + 1] = sy;
        out[sp + 2] = sz;
      }
    }
  }
}

extern "C" void kernel_launch(void* const* d_in, const int* in_sizes, int n_in,
                              void* d_out, int out_size, void* d_ws, size_t ws_size,
                              hipStream_t stream) {
  const float* coords = (const float*)d_in[1];  // (1, N, 3) f32
  const float* cell = (const float*)d_in[2];    // (3, 3) f32
  int P = out_size / 5;

  clk_wrapbin<<<CLK_NATOMS / 256, 256, 0, stream>>>(coords, cell);
  clk_cscan<<<1, 1024, 0, stream>>>();
  clk_scatter<<<CLK_NATOMS / 256, 256, 0, stream>>>();
  clk_count<<<CLK_PWAVES / 8, 512, 0, stream>>>();
  clk_emit<<<CLK_PWAVES / 8, 512, 0, stream>>>((int*)d_out, P);
}

// Round 21
// 135.685 us; speedup vs baseline: 2.8879x; 2.8879x over previous
//
#include <hip/hip_runtime.h>

#define CLN_NATOMS 8192
#define CLN_NSHIFT 14
#define CLN_NROWS (CLN_NSHIFT * CLN_NATOMS)  // 114688 rows = (k, i)
#define CLN_NTILE 112                        // tiles of 1024 rows
#define CLN_NCELL 512                        // 8x8x8 spatial bins
#define CLN_CAP 128                          // max hits per row (k=0 max ~90)
#define CLN_PWAVES 8192                      // persistent waves (1024 blk x 8)
#define CLN_C2 ((float)(5.2 * 5.2))          // f32 compare (JAX weak promotion)
#define CLN_R 5.35f                          // candidate interval half-width

__device__ const int cln_shifts[CLN_NSHIFT][3] = {
    {0, 0, 0},
    {-1, 0, 0}, {-1, -1, 0}, {0, -1, 0}, {1, -1, 0},
    {-1, 1, -1}, {0, 1, -1}, {1, 1, -1}, {-1, 0, -1},
    {0, 0, -1}, {1, 0, -1}, {-1, -1, -1}, {0, -1, -1}, {1, -1, -1}};

// Module-owned scratch (d_ws unused). Everything read is rewritten each call.
__device__ float4 cln_pp[CLN_NATOMS];      // wrapped coords
__device__ int cln_cid[CLN_NATOMS];        // cell id per atom
__device__ float4 cln_sorted[CLN_NATOMS];  // bin-sorted coords, .w = original i
__device__ unsigned cln_cstart[CLN_NCELL + 1];
__device__ unsigned cln_cfill0[CLN_NCELL]; // zero-based scatter counters
__device__ unsigned cln_nalive;            // alive-row count
__device__ unsigned cln_alist[CLN_NROWS];  // alive row ids (k<<13 | i)
__device__ int cln_jbuf[(size_t)CLN_NROWS * CLN_CAP];  // per-row sorted hit j's
__device__ unsigned cln_cnt[CLN_NROWS];
__device__ unsigned cln_tot[CLN_NTILE];    // per-tile totals (atomic, order-free)
__device__ float4 cln_dg;                  // cell diagonal
__device__ float4 cln_cinv;                // 8/diag per axis
__device__ float4 cln_sf[CLN_NSHIFT];      // s * diag (f32, __fmul_rn)

// Slab prune: d2<=c2 forces shifted atom i into a cutoff-wide boundary slab.
__device__ __forceinline__ bool cln_alive_f(float xi, float yi, float zi, int sx,
                                            int sy, int sz, float dgx, float dgy,
                                            float dgz) {
  bool a = true;
  if (sx < 0) a = a && (xi >= dgx - 5.3f); else if (sx > 0) a = a && (xi <= 5.3f);
  if (sy < 0) a = a && (yi >= dgy - 5.3f); else if (sy > 0) a = a && (yi <= 5.3f);
  if (sz < 0) a = a && (zi >= dgz - 5.3f); else if (sz > 0) a = a && (zi <= 5.3f);
  return a;
}

// Candidate cell range on one axis (monotone-rounding safe, 0.14 slack).
__device__ __forceinline__ void cln_crange(float t, float ci, int& lo, int& hi) {
  lo = max(0, (int)(fmaxf(t - CLN_R, 0.f) * ci));
  hi = min(7, (int)(fmaxf(t + CLN_R, 0.f) * ci));
}

__device__ __forceinline__ unsigned cln_iscan(unsigned v, int lane) {
  for (int off = 1; off < 64; off <<= 1) {
    unsigned t = __shfl_up(v, off);
    if (lane >= off) v += t;
  }
  return v;
}

// --- L1: wrap + cell-id; zero cnt/tot/cfill0/nalive; publish constants ------
// frac = x @ inv(cell); frac -= floor(frac); w = frac @ cell   (f32 per-op RN)
__global__ __launch_bounds__(256) void cln_wrapbin(const float* __restrict__ coords,
                                                   const float* __restrict__ cell) {
  int i = blockIdx.x * blockDim.x + threadIdx.x;
  if (i >= CLN_NATOMS) return;
  if (i < CLN_NTILE) cln_tot[i] = 0u;
  if (i < CLN_NCELL) cln_cfill0[i] = 0u;
  if (i == 0) cln_nalive = 0u;
#pragma unroll
  for (int k = 0; k < CLN_NSHIFT; ++k) cln_cnt[(k << 13) + i] = 0u;  // coalesced

  float dgx = (float)sqrt((double)cell[0] * cell[0] + (double)cell[3] * cell[3] +
                          (double)cell[6] * cell[6]);
  float dgy = (float)sqrt((double)cell[1] * cell[1] + (double)cell[4] * cell[4] +
                          (double)cell[7] * cell[7]);
  float dgz = (float)sqrt((double)cell[2] * cell[2] + (double)cell[5] * cell[5] +
                          (double)cell[8] * cell[8]);
  float cix = 8.0f / dgx, ciy = 8.0f / dgy, ciz = 8.0f / dgz;
  if (i == 0) {
    cln_dg = make_float4(dgx, dgy, dgz, 0.f);
    cln_cinv = make_float4(cix, ciy, ciz, 0.f);
    for (int k = 0; k < CLN_NSHIFT; ++k)
      cln_sf[k] = make_float4(__fmul_rn((float)cln_shifts[k][0], dgx),
                              __fmul_rn((float)cln_shifts[k][1], dgy),
                              __fmul_rn((float)cln_shifts[k][2], dgz), 0.f);
  }

  double a00 = cell[0], a01 = cell[1], a02 = cell[2];
  double a10 = cell[3], a11 = cell[4], a12 = cell[5];
  double a20 = cell[6], a21 = cell[7], a22 = cell[8];
  double det = a00 * (a11 * a22 - a12 * a21) - a01 * (a10 * a22 - a12 * a20) +
               a02 * (a10 * a21 - a11 * a20);
  double id = 1.0 / det;
  float inv[3][3];
  inv[0][0] = (float)((a11 * a22 - a12 * a21) * id);
  inv[0][1] = (float)(-(a01 * a22 - a02 * a21) * id);
  inv[0][2] = (float)((a01 * a12 - a02 * a11) * id);
  inv[1][0] = (float)(-(a10 * a22 - a12 * a20) * id);
  inv[1][1] = (float)((a00 * a22 - a02 * a20) * id);
  inv[1][2] = (float)(-(a00 * a12 - a02 * a10) * id);
  inv[2][0] = (float)((a10 * a21 - a11 * a20) * id);
  inv[2][1] = (float)(-(a00 * a21 - a01 * a20) * id);
  inv[2][2] = (float)((a00 * a11 - a01 * a10) * id);

  float x = coords[3 * i], y = coords[3 * i + 1], z = coords[3 * i + 2];
  float fr[3], w[3];
#pragma unroll
  for (int c = 0; c < 3; ++c) {
    float f = __fadd_rn(__fadd_rn(__fmul_rn(x, inv[0][c]), __fmul_rn(y, inv[1][c])),
                        __fmul_rn(z, inv[2][c]));
    fr[c] = __fsub_rn(f, floorf(f));
  }
#pragma unroll
  for (int c = 0; c < 3; ++c) {
    w[c] = __fadd_rn(
        __fadd_rn(__fmul_rn(fr[0], cell[0 * 3 + c]), __fmul_rn(fr[1], cell[1 * 3 + c])),
        __fmul_rn(fr[2], cell[2 * 3 + c]));
  }
  cln_pp[i] = make_float4(w[0], w[1], w[2], 0.0f);
  int cx = min(7, (int)(w[0] * cix));
  int cy = min(7, (int)(w[1] * ciy));
  int cz = min(7, (int)(w[2] * ciz));
  cln_cid[i] = (cz * 8 + cy) * 8 + cx;  // x fastest -> contiguous x-runs
}

// --- L2: scatter: 16 blocks x 512. Each block REDUNDANTLY builds the 512-bin
// histogram from cid in LDS + scans it (deterministic, no cross-block dep);
// block 0 publishes cstart for count. Then each block scatters its 512 atoms
// via zero-based global cfill0 atomics and builds the alive-row list.
// (intra-cell order and alist order nondeterministic; both output-invariant)
__global__ __launch_bounds__(512) void cln_scatter() {
  __shared__ unsigned h[CLN_NCELL];
  __shared__ unsigned sc[CLN_NCELL];
  int tid = threadIdx.x;
  h[tid] = 0u;
  __syncthreads();
#pragma unroll
  for (int r = 0; r < 16; ++r) atomicAdd(&h[cln_cid[tid + r * 512]], 1u);
  __syncthreads();
  unsigned v = h[tid];
  unsigned acc = v;
  for (int off = 1; off < CLN_NCELL; off <<= 1) {
    unsigned a = (tid >= off) ? h[tid - off] : 0u;
    __syncthreads();
    acc += a;
    h[tid] = acc;
    __syncthreads();
  }
  sc[tid] = acc - v;  // exclusive cell start
  if (blockIdx.x == 0) {
    cln_cstart[tid] = acc - v;
    if (tid == CLN_NCELL - 1) cln_cstart[CLN_NCELL] = acc;
  }
  __syncthreads();

  int i = blockIdx.x * 512 + tid;
  float4 p = cln_pp[i];
  int c = cln_cid[i];
  unsigned pos = sc[c] + atomicAdd(&cln_cfill0[c], 1u);
  float4 ps = p;
  ps.w = __int_as_float(i);
  cln_sorted[pos] = ps;

  // alive (k,i) row list
  float4 dg = cln_dg;
  unsigned rows[CLN_NSHIFT];
  int m = 0;
  rows[m++] = (unsigned)i;  // k = 0 always alive
#pragma unroll
  for (int k = 1; k < CLN_NSHIFT; ++k) {
    if (cln_alive_f(p.x, p.y, p.z, cln_shifts[k][0], cln_shifts[k][1],
                    cln_shifts[k][2], dg.x, dg.y, dg.z))
      rows[m++] = (unsigned)((k << 13) + i);
  }
  unsigned base = atomicAdd(&cln_nalive, (unsigned)m);
  for (int q = 0; q < m; ++q) cln_alist[base + q] = rows[q];
}

// --- L3: count: persistent waves over ALIVE rows (balanced); per row:
// cell-list candidates -> LDS bitmask -> sorted compact j-list + count.
// Row count ALSO accumulated into per-tile total via one fire-and-forget
// atomicAdd (NO fence/readback; tot complete at kernel boundary).
// Skip test is wave-uniform from the reconverged mask (round-14 lesson). -----
__global__ __launch_bounds__(512) void cln_count() {
  __shared__ uint4 smask[8][64];  // 1KB mask per wave
  int wslot = threadIdx.x >> 6;
  int lane = threadIdx.x & 63;
  unsigned* lm = (unsigned*)smask[wslot];
  unsigned na = cln_nalive;
  float4 cinv = cln_cinv;

  for (unsigned w = blockIdx.x * 8 + wslot; w < na; w += CLN_PWAVES) {
    unsigned row = cln_alist[w];
    int k = row >> 13, i = row & (CLN_NATOMS - 1);
    float4 sc = cln_sf[k];
    float4 pi = cln_pp[i];
    smask[wslot][lane] = make_uint4(0u, 0u, 0u, 0u);

    int xlo, xhi, ylo, yhi, zlo, zhi;
    cln_crange(__fadd_rn(pi.x, sc.x), cinv.x, xlo, xhi);
    cln_crange(__fadd_rn(pi.y, sc.y), cinv.y, ylo, yhi);
    cln_crange(__fadd_rn(pi.z, sc.z), cinv.z, zlo, zhi);

    for (int cz = zlo; cz <= zhi; ++cz) {
      for (int cy = ylo; cy <= yhi; ++cy) {
        int idb = (cz * 8 + cy) * 8;
        unsigned b = cln_cstart[idb + xlo], e = cln_cstart[idb + xhi + 1];
        for (unsigned t = b + lane; t < e; t += 64) {
          float4 pj = cln_sorted[t];
          int j = __float_as_int(pj.w);
          float dx = __fadd_rn(__fsub_rn(pi.x, pj.x), sc.x);
          float dy = __fadd_rn(__fsub_rn(pi.y, pj.y), sc.y);
          float dz = __fadd_rn(__fsub_rn(pi.z, pj.z), sc.z);
          float d2 = __fadd_rn(__fadd_rn(__fmul_rn(dx, dx), __fmul_rn(dy, dy)),
                               __fmul_rn(dz, dz));
          bool ok = (d2 <= CLN_C2) && (k != 0 || i < j);
          if (ok) atomicOr(&lm[(unsigned)j >> 5], 1u << (j & 31));
        }
      }
    }
    __threadfence_block();  // drain LDS atomics; all lanes reconverged here

    const unsigned long long* mrow = (const unsigned long long*)lm;
    unsigned long long m0 = mrow[lane];       // j in [64*lane, 64*lane+64)
    unsigned long long m1 = mrow[64 + lane];  // j in [4096+64*lane, ...)
    if (__ballot((m0 | m1) != 0ull) == 0ull) continue;  // wave-uniform skip

    unsigned c0 = (unsigned)__popcll(m0), c1 = (unsigned)__popcll(m1);
    unsigned s0 = cln_iscan(c0, lane);
    unsigned T0 = __shfl(s0, 63);
    unsigned e0 = s0 - c0;
    unsigned s1 = cln_iscan(c1, lane);
    unsigned T1 = __shfl(s1, 63);
    unsigned e1 = T0 + s1 - c1;

    size_t jb = (size_t)row * CLN_CAP;
    unsigned p = e0;
    unsigned long long m = m0;
    while (m) {
      int b = __ffsll((long long)m) - 1;
      m &= m - 1;
      if (p < CLN_CAP) cln_jbuf[jb + p] = (lane << 6) + b;
      ++p;
    }
    p = e1;
    m = m1;
    while (m) {
      int b = __ffsll((long long)m) - 1;
      m &= m - 1;
      if (p < CLN_CAP) cln_jbuf[jb + p] = ((64 + lane) << 6) + b;
      ++p;
    }
    if (lane == 0) {
      unsigned cv = min(T0 + T1, (unsigned)CLN_CAP);
      cln_cnt[row] = cv;
      atomicAdd(&cln_tot[row >> 10], cv);  // order-free tile total
    }
  }
}

// --- L4: emit: persistent waves over alive rows; per row: tile base from tot
// prefix (<=112, L2-hot, 2 loads/lane) + within-tile exclusive offset summed
// directly from cnt (<=16 loads/lane), then lanes copy the compact j-list into
// [ i xP | j xP | (sx,sy,sz) xP ] coalesced. (Validated in round 20's emit.) -
__global__ __launch_bounds__(512) void cln_emit(int* __restrict__ out, int P) {
  int wslot = threadIdx.x >> 6;
  int lane = threadIdx.x & 63;
  unsigned na = cln_nalive;

  for (unsigned w = blockIdx.x * 8 + wslot; w < na; w += CLN_PWAVES) {
    unsigned row = cln_alist[w];
    unsigned c = cln_cnt[row];  // wave-uniform load
    if (c == 0) continue;       // uniform branch
    int tile = (int)(row >> 10);
    unsigned tb = (unsigned)tile << 10;
    unsigned local = row & 1023u;

    unsigned v = 0;
    if (lane < tile) v = cln_tot[lane];
    if (64 + lane < tile) v += cln_tot[64 + lane];
    for (unsigned q = lane; q < local; q += 64) v += cln_cnt[tb + q];
#pragma unroll
    for (int off = 32; off; off >>= 1) v += __shfl_down(v, off);
    unsigned off0 = __shfl(v, 0);

    int k = row >> 13, i = row & (CLN_NATOMS - 1);
    int sx = cln_shifts[k][0], sy = cln_shifts[k][1], sz = cln_shifts[k][2];
    size_t jb = (size_t)row * CLN_CAP;
    for (unsigned q = lane; q < c; q += 64) {
      unsigned p = off0 + q;
      if (p < (unsigned)P) {
        out[p] = i;
        out[P + p] = cln_jbuf[jb + q];
        unsigned sp = 2u * (unsigned)P + 3u * p;
        out[sp] = sx;
        out[sp + 1] = sy;
        out[sp + 2] = sz;
      }
    }
  }
}

extern "C" void kernel_launch(void* const* d_in, const int* in_sizes, int n_in,
                              void* d_out, int out_size, void* d_ws, size_t ws_size,
                              hipStream_t stream) {
  const float* coords = (const float*)d_in[1];  // (1, N, 3) f32
  const float* cell = (const float*)d_in[2];    // (3, 3) f32
  int P = out_size / 5;

  cln_wrapbin<<<CLN_NATOMS / 256, 256, 0, stream>>>(coords, cell);
  cln_scatter<<<16, 512, 0, stream>>>();
  cln_count<<<CLN_PWAVES / 8, 512, 0, stream>>>();
  cln_emit<<<CLN_PWAVES / 8, 512, 0, stream>>>((int*)d_out, P);
}

// Round 22
// 45.582 us; speedup vs baseline: 8.5965x; 2.9767x over previous
//
#include <hip/hip_runtime.h>

#define CLM_NATOMS 8192
#define CLM_NSHIFT 14
#define CLM_NROWS (CLM_NSHIFT * CLM_NATOMS)  // 114688 rows = (k, i)
#define CLM_NTILE 112                        // tiles of 1024 rows
#define CLM_NCELL 512                        // 8x8x8 spatial bins
#define CLM_CAP 128                          // max hits per row (k=0 max ~90)
#define CLM_PWAVES 8192                      // persistent waves (1024 blk x 8)
#define CLM_C2 ((float)(5.2 * 5.2))          // f32 compare (JAX weak promotion)
#define CLM_R 5.35f                          // candidate interval half-width

__device__ const int clm_shifts[CLM_NSHIFT][3] = {
    {0, 0, 0},
    {-1, 0, 0}, {-1, -1, 0}, {0, -1, 0}, {1, -1, 0},
    {-1, 1, -1}, {0, 1, -1}, {1, 1, -1}, {-1, 0, -1},
    {0, 0, -1}, {1, 0, -1}, {-1, -1, -1}, {0, -1, -1}, {1, -1, -1}};

// Module-owned scratch (d_ws unused). Everything read is rewritten each call.
__device__ float4 clm_pp[CLM_NATOMS];      // wrapped coords
__device__ int clm_cid[CLM_NATOMS];        // cell id per atom
__device__ float4 clm_sorted[CLM_NATOMS];  // bin-sorted coords, .w = original i
__device__ unsigned clm_cstart[CLM_NCELL + 1];
__device__ unsigned clm_cfill0[CLM_NCELL]; // zero-based scatter counters
__device__ unsigned clm_nalive;            // alive-row count
__device__ unsigned clm_alist[CLM_NROWS];  // alive row ids (k<<13 | i)
__device__ int clm_jbuf[(size_t)CLM_NROWS * CLM_CAP];  // per-row sorted hit j's
__device__ unsigned clm_cnt[CLM_NROWS];
__device__ unsigned clm_off[CLM_NROWS];    // exclusive offset WITHIN tile
__device__ unsigned clm_tot[CLM_NTILE];    // per-tile totals (s1 writes)
__device__ float4 clm_dg;                  // cell diagonal
__device__ float4 clm_cinv;                // 8/diag per axis
__device__ float4 clm_sf[CLM_NSHIFT];      // s * diag (f32, __fmul_rn)

// Slab prune: d2<=c2 forces shifted atom i into a cutoff-wide boundary slab.
__device__ __forceinline__ bool clm_alive_f(float xi, float yi, float zi, int sx,
                                            int sy, int sz, float dgx, float dgy,
                                            float dgz) {
  bool a = true;
  if (sx < 0) a = a && (xi >= dgx - 5.3f); else if (sx > 0) a = a && (xi <= 5.3f);
  if (sy < 0) a = a && (yi >= dgy - 5.3f); else if (sy > 0) a = a && (yi <= 5.3f);
  if (sz < 0) a = a && (zi >= dgz - 5.3f); else if (sz > 0) a = a && (zi <= 5.3f);
  return a;
}

// Candidate cell range on one axis (monotone-rounding safe, 0.14 slack).
__device__ __forceinline__ void clm_crange(float t, float ci, int& lo, int& hi) {
  lo = max(0, (int)(fmaxf(t - CLM_R, 0.f) * ci));
  hi = min(7, (int)(fmaxf(t + CLM_R, 0.f) * ci));
}

__device__ __forceinline__ unsigned clm_iscan(unsigned v, int lane) {
  for (int off = 1; off < 64; off <<= 1) {
    unsigned t = __shfl_up(v, off);
    if (lane >= off) v += t;
  }
  return v;
}

// --- L1: wrap + cell-id; zero cnt/cfill0/nalive; publish constants ----------
// frac = x @ inv(cell); frac -= floor(frac); w = frac @ cell   (f32 per-op RN)
__global__ __launch_bounds__(256) void clm_wrapbin(const float* __restrict__ coords,
                                                   const float* __restrict__ cell) {
  int i = blockIdx.x * blockDim.x + threadIdx.x;
  if (i >= CLM_NATOMS) return;
  if (i < CLM_NCELL) clm_cfill0[i] = 0u;
  if (i == 0) clm_nalive = 0u;
#pragma unroll
  for (int k = 0; k < CLM_NSHIFT; ++k) clm_cnt[(k << 13) + i] = 0u;  // coalesced

  float dgx = (float)sqrt((double)cell[0] * cell[0] + (double)cell[3] * cell[3] +
                          (double)cell[6] * cell[6]);
  float dgy = (float)sqrt((double)cell[1] * cell[1] + (double)cell[4] * cell[4] +
                          (double)cell[7] * cell[7]);
  float dgz = (float)sqrt((double)cell[2] * cell[2] + (double)cell[5] * cell[5] +
                          (double)cell[8] * cell[8]);
  float cix = 8.0f / dgx, ciy = 8.0f / dgy, ciz = 8.0f / dgz;
  if (i == 0) {
    clm_dg = make_float4(dgx, dgy, dgz, 0.f);
    clm_cinv = make_float4(cix, ciy, ciz, 0.f);
    for (int k = 0; k < CLM_NSHIFT; ++k)
      clm_sf[k] = make_float4(__fmul_rn((float)clm_shifts[k][0], dgx),
                              __fmul_rn((float)clm_shifts[k][1], dgy),
                              __fmul_rn((float)clm_shifts[k][2], dgz), 0.f);
  }

  double a00 = cell[0], a01 = cell[1], a02 = cell[2];
  double a10 = cell[3], a11 = cell[4], a12 = cell[5];
  double a20 = cell[6], a21 = cell[7], a22 = cell[8];
  double det = a00 * (a11 * a22 - a12 * a21) - a01 * (a10 * a22 - a12 * a20) +
               a02 * (a10 * a21 - a11 * a20);
  double id = 1.0 / det;
  float inv[3][3];
  inv[0][0] = (float)((a11 * a22 - a12 * a21) * id);
  inv[0][1] = (float)(-(a01 * a22 - a02 * a21) * id);
  inv[0][2] = (float)((a01 * a12 - a02 * a11) * id);
  inv[1][0] = (float)(-(a10 * a22 - a12 * a20) * id);
  inv[1][1] = (float)((a00 * a22 - a02 * a20) * id);
  inv[1][2] = (float)(-(a00 * a12 - a02 * a10) * id);
  inv[2][0] = (float)((a10 * a21 - a11 * a20) * id);
  inv[2][1] = (float)(-(a00 * a21 - a01 * a20) * id);
  inv[2][2] = (float)((a00 * a11 - a01 * a10) * id);

  float x = coords[3 * i], y = coords[3 * i + 1], z = coords[3 * i + 2];
  float fr[3], w[3];
#pragma unroll
  for (int c = 0; c < 3; ++c) {
    float f = __fadd_rn(__fadd_rn(__fmul_rn(x, inv[0][c]), __fmul_rn(y, inv[1][c])),
                        __fmul_rn(z, inv[2][c]));
    fr[c] = __fsub_rn(f, floorf(f));
  }
#pragma unroll
  for (int c = 0; c < 3; ++c) {
    w[c] = __fadd_rn(
        __fadd_rn(__fmul_rn(fr[0], cell[0 * 3 + c]), __fmul_rn(fr[1], cell[1 * 3 + c])),
        __fmul_rn(fr[2], cell[2 * 3 + c]));
  }
  clm_pp[i] = make_float4(w[0], w[1], w[2], 0.0f);
  int cx = min(7, (int)(w[0] * cix));
  int cy = min(7, (int)(w[1] * ciy));
  int cz = min(7, (int)(w[2] * ciz));
  clm_cid[i] = (cz * 8 + cy) * 8 + cx;  // x fastest -> contiguous x-runs
}

// --- L2: scatter: 16 blocks x 512. Each block REDUNDANTLY builds the 512-bin
// histogram from cid in LDS + scans it (deterministic, identical in every
// block, no cross-block dependency/spin); block 0 publishes cstart. Then each
// block scatters its 512 atoms via zero-based cfill0 atomics and builds the
// alive-row list. (intra-cell order and alist order nondeterministic; both
// output-invariant: hits keyed by original index, rows own their slots) ------
__global__ __launch_bounds__(512) void clm_scatter() {
  __shared__ unsigned h[CLM_NCELL];
  __shared__ unsigned sc[CLM_NCELL];
  int tid = threadIdx.x;
  h[tid] = 0u;
  __syncthreads();
#pragma unroll
  for (int r = 0; r < 16; ++r) atomicAdd(&h[clm_cid[tid + r * 512]], 1u);
  __syncthreads();
  unsigned v = h[tid];
  unsigned acc = v;
  for (int off = 1; off < CLM_NCELL; off <<= 1) {
    unsigned a = (tid >= off) ? h[tid - off] : 0u;
    __syncthreads();
    acc += a;
    h[tid] = acc;
    __syncthreads();
  }
  sc[tid] = acc - v;  // exclusive cell start
  if (blockIdx.x == 0) {
    clm_cstart[tid] = acc - v;
    if (tid == CLM_NCELL - 1) clm_cstart[CLM_NCELL] = acc;
  }
  __syncthreads();

  int i = blockIdx.x * 512 + tid;
  float4 p = clm_pp[i];
  int c = clm_cid[i];
  unsigned pos = sc[c] + atomicAdd(&clm_cfill0[c], 1u);
  float4 ps = p;
  ps.w = __int_as_float(i);
  clm_sorted[pos] = ps;

  // alive (k,i) row list
  float4 dg = clm_dg;
  unsigned rows[CLM_NSHIFT];
  int m = 0;
  rows[m++] = (unsigned)i;  // k = 0 always alive
#pragma unroll
  for (int k = 1; k < CLM_NSHIFT; ++k) {
    if (clm_alive_f(p.x, p.y, p.z, clm_shifts[k][0], clm_shifts[k][1],
                    clm_shifts[k][2], dg.x, dg.y, dg.z))
      rows[m++] = (unsigned)((k << 13) + i);
  }
  unsigned base = atomicAdd(&clm_nalive, (unsigned)m);
  for (int q = 0; q < m; ++q) clm_alist[base + q] = rows[q];
}

// --- L3: count: persistent waves over ALIVE rows (balanced); per row:
// cell-list candidates -> LDS bitmask -> sorted compact j-list + count.
// ROUND-15 VERBATIM: no atomics, no fences beyond the LDS drain; skip test is
// wave-uniform from the reconverged mask (round-14 lesson). ------------------
__global__ __launch_bounds__(512) void clm_count() {
  __shared__ uint4 smask[8][64];  // 1KB mask per wave
  int wslot = threadIdx.x >> 6;
  int lane = threadIdx.x & 63;
  unsigned* lm = (unsigned*)smask[wslot];
  unsigned na = clm_nalive;
  float4 cinv = clm_cinv;

  for (unsigned w = blockIdx.x * 8 + wslot; w < na; w += CLM_PWAVES) {
    unsigned row = clm_alist[w];
    int k = row >> 13, i = row & (CLM_NATOMS - 1);
    float4 sc = clm_sf[k];
    float4 pi = clm_pp[i];
    smask[wslot][lane] = make_uint4(0u, 0u, 0u, 0u);

    int xlo, xhi, ylo, yhi, zlo, zhi;
    clm_crange(__fadd_rn(pi.x, sc.x), cinv.x, xlo, xhi);
    clm_crange(__fadd_rn(pi.y, sc.y), cinv.y, ylo, yhi);
    clm_crange(__fadd_rn(pi.z, sc.z), cinv.z, zlo, zhi);

    for (int cz = zlo; cz <= zhi; ++cz) {
      for (int cy = ylo; cy <= yhi; ++cy) {
        int idb = (cz * 8 + cy) * 8;
        unsigned b = clm_cstart[idb + xlo], e = clm_cstart[idb + xhi + 1];
        for (unsigned t = b + lane; t < e; t += 64) {
          float4 pj = clm_sorted[t];
          int j = __float_as_int(pj.w);
          float dx = __fadd_rn(__fsub_rn(pi.x, pj.x), sc.x);
          float dy = __fadd_rn(__fsub_rn(pi.y, pj.y), sc.y);
          float dz = __fadd_rn(__fsub_rn(pi.z, pj.z), sc.z);
          float d2 = __fadd_rn(__fadd_rn(__fmul_rn(dx, dx), __fmul_rn(dy, dy)),
                               __fmul_rn(dz, dz));
          bool ok = (d2 <= CLM_C2) && (k != 0 || i < j);
          if (ok) atomicOr(&lm[(unsigned)j >> 5], 1u << (j & 31));
        }
      }
    }
    __threadfence_block();  // drain LDS atomics; all lanes reconverged here

    const unsigned long long* mrow = (const unsigned long long*)lm;
    unsigned long long m0 = mrow[lane];       // j in [64*lane, 64*lane+64)
    unsigned long long m1 = mrow[64 + lane];  // j in [4096+64*lane, ...)
    if (__ballot((m0 | m1) != 0ull) == 0ull) continue;  // wave-uniform skip

    unsigned c0 = (unsigned)__popcll(m0), c1 = (unsigned)__popcll(m1);
    unsigned s0 = clm_iscan(c0, lane);
    unsigned T0 = __shfl(s0, 63);
    unsigned e0 = s0 - c0;
    unsigned s1 = clm_iscan(c1, lane);
    unsigned T1 = __shfl(s1, 63);
    unsigned e1 = T0 + s1 - c1;

    size_t jb = (size_t)row * CLM_CAP;
    unsigned p = e0;
    unsigned long long m = m0;
    while (m) {
      int b = __ffsll((long long)m) - 1;
      m &= m - 1;
      if (p < CLM_CAP) clm_jbuf[jb + p] = (lane << 6) + b;
      ++p;
    }
    p = e1;
    m = m1;
    while (m) {
      int b = __ffsll((long long)m) - 1;
      m &= m - 1;
      if (p < CLM_CAP) clm_jbuf[jb + p] = ((64 + lane) << 6) + b;
      ++p;
    }
    if (lane == 0) clm_cnt[row] = min(T0 + T1, (unsigned)CLM_CAP);
  }
}

// --- L4: per-1024-row tile exclusive scan + tile total (round-15 verbatim) --
__global__ __launch_bounds__(1024) void clm_s1() {
  __shared__ unsigned sd[1024];
  int t = threadIdx.x;
  int gid = blockIdx.x * 1024 + t;
  unsigned v = clm_cnt[gid];
  sd[t] = v;
  __syncthreads();
  unsigned acc = v;
  for (int off = 1; off < 1024; off <<= 1) {
    unsigned a = (t >= off) ? sd[t - off] : 0u;
    __syncthreads();
    acc += a;
    sd[t] = acc;
    __syncthreads();
  }
  clm_off[gid] = acc - v;
  if (t == 1023) clm_tot[blockIdx.x] = acc;
}

// --- L5: emit: persistent waves over alive rows; per row: reduce preceding
// tile totals (<=112, L2-hot) inline for the base, then lanes copy the compact
// j-list into [ i xP | j xP | (sx,sy,sz) xP ] coalesced (round-15 verbatim) --
__global__ __launch_bounds__(512) void clm_emit(int* __restrict__ out, int P) {
  int wslot = threadIdx.x >> 6;
  int lane = threadIdx.x & 63;
  unsigned na = clm_nalive;

  for (unsigned w = blockIdx.x * 8 + wslot; w < na; w += CLM_PWAVES) {
    unsigned row = clm_alist[w];
    unsigned c = clm_cnt[row];  // wave-uniform load
    if (c == 0) continue;       // uniform branch
    int tile = row >> 10;       // 1024 rows per tile
    unsigned v = 0;
    if (lane < tile) v = clm_tot[lane];
    if (64 + lane < tile) v += clm_tot[64 + lane];
#pragma unroll
    for (int off = 32; off; off >>= 1) v += __shfl_down(v, off);
    unsigned tbase = __shfl(v, 0);

    unsigned off0 = clm_off[row] + tbase;
    int k = row >> 13, i = row & (CLM_NATOMS - 1);
    int sx = clm_shifts[k][0], sy = clm_shifts[k][1], sz = clm_shifts[k][2];
    size_t jb = (size_t)row * CLM_CAP;
    for (unsigned q = lane; q < c; q += 64) {
      unsigned p = off0 + q;
      if (p < (unsigned)P) {
        out[p] = i;
        out[P + p] = clm_jbuf[jb + q];
        unsigned sp = 2u * (unsigned)P + 3u * p;
        out[sp] = sx;
        out[sp + 1] = sy;
        out[sp + 2] = sz;
      }
    }
  }
}

extern "C" void kernel_launch(void* const* d_in, const int* in_sizes, int n_in,
                              void* d_out, int out_size, void* d_ws, size_t ws_size,
                              hipStream_t stream) {
  const float* coords = (const float*)d_in[1];  // (1, N, 3) f32
  const float* cell = (const float*)d_in[2];    // (3, 3) f32
  int P = out_size / 5;

  clm_wrapbin<<<CLM_NATOMS / 256, 256, 0, stream>>>(coords, cell);
  clm_scatter<<<16, 512, 0, stream>>>();
  clm_count<<<CLM_PWAVES / 8, 512, 0, stream>>>();
  clm_s1<<<CLM_NTILE, 1024, 0, stream>>>();
  clm_emit<<<CLM_PWAVES / 8, 512, 0, stream>>>((int*)d_out, P);
}